// Round 3
// baseline (1363.519 us; speedup 1.0000x reference)
//
#include <hip/hip_runtime.h>

// CascadeImageGuideUpsample: 2 iterations of
//   img_hf = 2*bilinear(img->2H) - up2(down2(bilinear(img->2H)))
//   mask   = softmax(conv3x3(concat(nearest2x(feat), img_hf)))  [25 ch]
//   seg    = carafe(nearest2x(seg), mask); feat = carafe(nearest2x(feat), mask)
//
// Exact resize algebra (half-pixel, antialias=False):
//   2x down  = 2x2 box average
//   2x up    = (0.25,0.75)/(0.75,0.25) separable stencil with edge clamp
//   384->384 = identity
// CARAFE(nearest2x(x)) : the 5x5 window at up-res maps to only 3x3 distinct
// source pixels -> fold 25 mask weights into 9 combined weights per pixel.

#define TPB 256

// ---------- down2: out[c,y,x] = avg of 2x2 block. out dims [C,H,W], in [C,2H,2W]
__global__ __launch_bounds__(TPB) void down2_kernel(
    const float* __restrict__ in, float* __restrict__ out, int C, int H, int W) {
  int idx = blockIdx.x * TPB + threadIdx.x;
  int N = C * H * W;
  if (idx >= N) return;
  int x = idx % W; int t = idx / W; int y = t % H; int c = t / H;
  const float* p = in + ((c * 2 * H) + 2 * y) * (2 * W) + 2 * x;
  out[idx] = 0.25f * (p[0] + p[1] + p[2 * W] + p[2 * W + 1]);
}

// ---------- highboost: out[c,y,x] = 2*base[c,y,x] - up2(lr)[c,y,x]
// base/out [C,2H,2W], lr [C,H,W]
__global__ __launch_bounds__(TPB) void highboost_kernel(
    const float* __restrict__ base, const float* __restrict__ lr,
    float* __restrict__ out, int C, int H, int W) {
  const int OH = 2 * H, OW = 2 * W;
  int idx = blockIdx.x * TPB + threadIdx.x;
  int N = C * OH * OW;
  if (idx >= N) return;
  int x = idx % OW; int t = idx / OW; int y = t % OH; int c = t / OH;
  int m = y >> 1; int ya, yb; float wya, wyb;
  if ((y & 1) == 0) { ya = (m - 1 < 0) ? 0 : m - 1; yb = m; wya = 0.25f; wyb = 0.75f; }
  else             { ya = m; yb = (m + 1 >= H) ? H - 1 : m + 1; wya = 0.75f; wyb = 0.25f; }
  int n = x >> 1; int xa, xb; float wxa, wxb;
  if ((x & 1) == 0) { xa = (n - 1 < 0) ? 0 : n - 1; xb = n; wxa = 0.25f; wxb = 0.75f; }
  else             { xa = n; xb = (n + 1 >= W) ? W - 1 : n + 1; wxa = 0.75f; wxb = 0.25f; }
  const float* p = lr + c * H * W;
  float up = wya * (wxa * p[ya * W + xa] + wxb * p[ya * W + xb])
           + wyb * (wxa * p[yb * W + xa] + wxb * p[yb * W + xb]);
  out[idx] = 2.0f * base[idx] - up;
}

// ---------- conv3x3(concat(nearest2x(feat), hf)) -> softmax over 25 channels
// feat [32,Hf,Wf], hf [3,2Hf,2Wf], w [25,35,3,3], b [25], mask out [25,(2Hf)*(2Wf)]
// Weights staged to LDS transposed: wl[(ic*9+tap)*28 + oc]  (oc contiguous, pad 28)
// P pixels per thread (pix and pix + Np/P strides) to amortize LDS reads.
template <int P>
__global__ __launch_bounds__(TPB) void conv_softmax_kernel(
    const float* __restrict__ feat, const float* __restrict__ hf,
    const float* __restrict__ w, const float* __restrict__ b,
    float* __restrict__ mask, int Hf, int Wf) {
  const int OH = 2 * Hf, OW = 2 * Wf;
  const int Np = OH * OW;
  __shared__ __align__(16) float wl[35 * 9 * 28];
  __shared__ float bl[25];
  for (int i = threadIdx.x; i < 35 * 9 * 25; i += TPB) {
    int oc = i % 25, it = i / 25;           // it = ic*9 + tap
    wl[it * 28 + oc] = w[oc * 315 + it];
  }
  if (threadIdx.x < 25) bl[threadIdx.x] = b[threadIdx.x];
  __syncthreads();

  const int chunk = Np / P;
  const int p0 = blockIdx.x * TPB + threadIdx.x;
  if (p0 >= chunk) return;

  float acc[P][25];
  int X[P], Y[P];
#pragma unroll
  for (int q = 0; q < P; ++q) {
    int pix = p0 + q * chunk;
    X[q] = pix % OW; Y[q] = pix / OW;
#pragma unroll
    for (int oc = 0; oc < 25; ++oc) acc[q][oc] = bl[oc];
  }
  const int fplane = Hf * Wf;

  for (int ky = 0; ky < 3; ++ky) {
    for (int kx = 0; kx < 3; ++kx) {
      const int tap = ky * 3 + kx;
      int foff[P], hoff[P]; bool val[P];
#pragma unroll
      for (int q = 0; q < P; ++q) {
        int yy = Y[q] + ky - 1, xx = X[q] + kx - 1;
        val[q] = (yy >= 0 && yy < OH && xx >= 0 && xx < OW);
        foff[q] = (yy >> 1) * Wf + (xx >> 1);   // nearest2x source
        hoff[q] = yy * OW + xx;
      }
      const float* wbase = wl + tap * 28;
      // 32 feat channels (nearest2x-indexed)
      for (int ic = 0; ic < 32; ++ic) {
        float v[P];
#pragma unroll
        for (int q = 0; q < P; ++q)
          v[q] = val[q] ? feat[ic * fplane + foff[q]] : 0.0f;
        const float* wp = wbase + ic * 252;     // (ic*9)*28
        float wv[28];
#pragma unroll
        for (int k = 0; k < 7; ++k)
          *(float4*)(wv + 4 * k) = *(const float4*)(wp + 4 * k);
#pragma unroll
        for (int oc = 0; oc < 25; ++oc)
#pragma unroll
          for (int q = 0; q < P; ++q) acc[q][oc] += v[q] * wv[oc];
      }
      // 3 high-frequency image channels
      for (int ic = 0; ic < 3; ++ic) {
        float v[P];
#pragma unroll
        for (int q = 0; q < P; ++q)
          v[q] = val[q] ? hf[ic * Np + hoff[q]] : 0.0f;
        const float* wp = wbase + (32 + ic) * 252;
        float wv[28];
#pragma unroll
        for (int k = 0; k < 7; ++k)
          *(float4*)(wv + 4 * k) = *(const float4*)(wp + 4 * k);
#pragma unroll
        for (int oc = 0; oc < 25; ++oc)
#pragma unroll
          for (int q = 0; q < P; ++q) acc[q][oc] += v[q] * wv[oc];
      }
    }
  }
  // softmax over the 25 taps + store
#pragma unroll
  for (int q = 0; q < P; ++q) {
    float mx = acc[q][0];
#pragma unroll
    for (int oc = 1; oc < 25; ++oc) mx = fmaxf(mx, acc[q][oc]);
    float s = 0.f;
#pragma unroll
    for (int oc = 0; oc < 25; ++oc) { acc[q][oc] = __expf(acc[q][oc] - mx); s += acc[q][oc]; }
    float inv = 1.0f / s;
    int pix = p0 + q * chunk;
#pragma unroll
    for (int oc = 0; oc < 25; ++oc) mask[oc * Np + pix] = acc[q][oc] * inv;
  }
}

// ---------- CARAFE on nearest2x input, folded to 3x3 source stencil
__device__ __forceinline__ void carafe_apply(
    const float* __restrict__ in, float* __restrict__ out, int C,
    int fplane, int Np, int pix, const float cw[9],
    const int sy[3], const int sx[3], int Wf) {
  for (int c = 0; c < C; ++c) {
    const float* p = in + c * fplane;
    const float* r0 = p + sy[0] * Wf;
    const float* r1 = p + sy[1] * Wf;
    const float* r2 = p + sy[2] * Wf;
    float acc = cw[0] * r0[sx[0]] + cw[1] * r0[sx[1]] + cw[2] * r0[sx[2]]
              + cw[3] * r1[sx[0]] + cw[4] * r1[sx[1]] + cw[5] * r1[sx[2]]
              + cw[6] * r2[sx[0]] + cw[7] * r2[sx[1]] + cw[8] * r2[sx[2]];
    out[c * Np + pix] = acc;
  }
}

__global__ __launch_bounds__(TPB) void carafe_kernel(
    const float* __restrict__ mask,
    const float* __restrict__ in0, float* __restrict__ out0, int C0,
    const float* __restrict__ in1, float* __restrict__ out1, int C1,
    int Hf, int Wf) {
  const int OH = 2 * Hf, OW = 2 * Wf;
  const int Np = OH * OW;
  int pix = blockIdx.x * TPB + threadIdx.x;
  if (pix >= Np) return;
  int x = pix % OW, y = pix / OW;

  float cw[9];
#pragma unroll
  for (int i = 0; i < 9; ++i) cw[i] = 0.f;
  int ry0 = (y - 2) >> 1, rx0 = (x - 2) >> 1;   // arithmetic shift = floor div
#pragma unroll
  for (int di = 0; di < 5; ++di) {
    int yy = y + di - 2;
    if (yy < 0 || yy >= OH) continue;           // zero padding tap
    int ry = (yy >> 1) - ry0;                   // 0..2
#pragma unroll
    for (int dj = 0; dj < 5; ++dj) {
      int xx = x + dj - 2;
      if (xx < 0 || xx >= OW) continue;
      int rx = (xx >> 1) - rx0;
      cw[ry * 3 + rx] += mask[(di * 5 + dj) * Np + pix];
    }
  }
  int sy[3], sx[3];
#pragma unroll
  for (int i = 0; i < 3; ++i) {                 // clamp; OOB rows/cols have cw==0
    int v = ry0 + i; sy[i] = v < 0 ? 0 : (v >= Hf ? Hf - 1 : v);
    int u = rx0 + i; sx[i] = u < 0 ? 0 : (u >= Wf ? Wf - 1 : u);
  }
  const int fplane = Hf * Wf;
  carafe_apply(in0, out0, C0, fplane, Np, pix, cw, sy, sx, Wf);
  if (in1 != nullptr) carafe_apply(in1, out1, C1, fplane, Np, pix, cw, sy, sx, Wf);
}

extern "C" void kernel_launch(void* const* d_in, const int* in_sizes, int n_in,
                              void* d_out, int out_size, void* d_ws, size_t ws_size,
                              hipStream_t stream) {
  (void)in_sizes; (void)n_in; (void)out_size; (void)ws_size;
  const float* feat = (const float*)d_in[0];  // [1,32,96,96]
  const float* seg  = (const float*)d_in[1];  // [1,19,96,96]
  const float* img  = (const float*)d_in[2];  // [1,3,384,384]
  const float* w0   = (const float*)d_in[3];  // [25,35,3,3]
  const float* b0   = (const float*)d_in[4];  // [25]
  const float* w1   = (const float*)d_in[5];
  const float* b1   = (const float*)d_in[6];
  float* out = (float*)d_out;                 // [1,19,384,384]

  float* ws   = (float*)d_ws;
  float* I192 = ws;                    // 3*192*192   = 110592
  float* I96  = I192 + 3 * 192 * 192;  // 3*96*96     = 27648
  float* HF   = I96  + 3 * 96 * 96;    // up to 3*384*384 = 442368
  float* MASK = HF   + 3 * 384 * 384;  // up to 25*384*384 = 3686400
  float* F1   = MASK + 25 * 384 * 384; // 32*192*192  = 1179648
  float* S1   = F1   + 32 * 192 * 192; // 19*192*192  = 700416
  // total = 6,147,072 floats = 24.6 MB of workspace

  // shared pre-pass: I192 = down2(img) (== bilinear 384->192); I96 = down2(I192)
  down2_kernel<<<432, TPB, 0, stream>>>(img, I192, 3, 192, 192);
  down2_kernel<<<108, TPB, 0, stream>>>(I192, I96, 3, 96, 96);

  // ---- iteration 0 (Hf=96) ----
  highboost_kernel<<<432, TPB, 0, stream>>>(I192, I96, HF, 3, 96, 96);
  conv_softmax_kernel<1><<<(96 * 96 * 4 + TPB - 1) / TPB, TPB, 0, stream>>>(
      feat, HF, w0, b0, MASK, 96, 96);
  carafe_kernel<<<(96 * 96 * 4 + TPB - 1) / TPB, TPB, 0, stream>>>(
      MASK, seg, S1, 19, feat, F1, 32, 96, 96);

  // ---- iteration 1 (Hf=192) ----
  highboost_kernel<<<1728, TPB, 0, stream>>>(img, I192, HF, 3, 192, 192);
  conv_softmax_kernel<2><<<(192 * 192 * 4 / 2 + TPB - 1) / TPB, TPB, 0, stream>>>(
      F1, HF, w1, b1, MASK, 192, 192);
  carafe_kernel<<<(192 * 192 * 4 + TPB - 1) / TPB, TPB, 0, stream>>>(
      MASK, S1, out, 19, nullptr, nullptr, 0, 192, 192);
}

// Round 4
// 334.878 us; speedup vs baseline: 4.0717x; 4.0717x over previous
//
#include <hip/hip_runtime.h>

// CascadeImageGuideUpsample: 2 iterations of
//   img_hf = 2*bilinear(img->2H) - up2(down2(bilinear(img->2H)))
//   mask   = softmax(conv3x3(concat(nearest2x(feat), img_hf)))  [25 ch]
//   seg    = carafe(nearest2x(seg), mask); feat = carafe(nearest2x(feat), mask)
//
// Exact resize algebra (half-pixel, antialias=False):
//   2x down = 2x2 box average; 2x up = (0.25,0.75) stencil w/ clamp; 384->384 = id.
// CARAFE(nearest2x(x)): 5x5 up-res window hits only 3x3 source pixels ->
// fold 25 mask weights into 9 per pixel.
//
// R3 fix: conv was scratch-bound (13KB spill/thread, WRITE_SIZE 966MB,
// VALUBusy 0.6%). New conv keeps ONLY acc[25] per thread; weights are
// wave-uniform -> scalar loads (s_load) + SGPR-sourced v_fmac. Weights
// repacked once per launch to wT[tap][ic][oc] (contiguous 25-float runs).

#define TPB 256

// ---------- repack: wT[(tap*35+ic)*25+oc] = w[oc*315+ic*9+tap]
__global__ __launch_bounds__(TPB) void repack_w_kernel(
    const float* __restrict__ w, float* __restrict__ wT) {
  int i = blockIdx.x * TPB + threadIdx.x;
  if (i >= 25 * 35 * 9) return;
  int oc = i % 25; int t = i / 25;        // t = tap*35 + ic
  int tap = t / 35; int ic = t % 35;
  wT[i] = w[oc * 315 + ic * 9 + tap];
}

// ---------- down2: out[c,y,x] = avg of 2x2 block. out [C,H,W], in [C,2H,2W]
__global__ __launch_bounds__(TPB) void down2_kernel(
    const float* __restrict__ in, float* __restrict__ out, int C, int H, int W) {
  int idx = blockIdx.x * TPB + threadIdx.x;
  int N = C * H * W;
  if (idx >= N) return;
  int x = idx % W; int t = idx / W; int y = t % H; int c = t / H;
  const float* p = in + ((c * 2 * H) + 2 * y) * (2 * W) + 2 * x;
  out[idx] = 0.25f * (p[0] + p[1] + p[2 * W] + p[2 * W + 1]);
}

// ---------- highboost: out = 2*base - up2(lr). base/out [C,2H,2W], lr [C,H,W]
__global__ __launch_bounds__(TPB) void highboost_kernel(
    const float* __restrict__ base, const float* __restrict__ lr,
    float* __restrict__ out, int C, int H, int W) {
  const int OH = 2 * H, OW = 2 * W;
  int idx = blockIdx.x * TPB + threadIdx.x;
  int N = C * OH * OW;
  if (idx >= N) return;
  int x = idx % OW; int t = idx / OW; int y = t % OH; int c = t / OH;
  int m = y >> 1; int ya, yb; float wya, wyb;
  if ((y & 1) == 0) { ya = (m - 1 < 0) ? 0 : m - 1; yb = m; wya = 0.25f; wyb = 0.75f; }
  else             { ya = m; yb = (m + 1 >= H) ? H - 1 : m + 1; wya = 0.75f; wyb = 0.25f; }
  int n = x >> 1; int xa, xb; float wxa, wxb;
  if ((x & 1) == 0) { xa = (n - 1 < 0) ? 0 : n - 1; xb = n; wxa = 0.25f; wxb = 0.75f; }
  else             { xa = n; xb = (n + 1 >= W) ? W - 1 : n + 1; wxa = 0.75f; wxb = 0.25f; }
  const float* p = lr + c * H * W;
  float up = wya * (wxa * p[ya * W + xa] + wxb * p[ya * W + xb])
           + wyb * (wxa * p[yb * W + xa] + wxb * p[yb * W + xb]);
  out[idx] = 2.0f * base[idx] - up;
}

// ---------- conv3x3(concat(nearest2x(feat), hf)) -> softmax over 25 channels
// feat [32,Hf,Wf], hf [3,2Hf,2Wf], wT [9*35*25] as [tap][ic][oc], b [25]
// mask out [25, (2Hf)*(2Wf)]. One thread = one output pixel; only acc[25]
// lives per-thread; weight reads are uniform -> scalar cache.
__global__ __launch_bounds__(TPB) void conv_softmax_kernel(
    const float* __restrict__ feat, const float* __restrict__ hf,
    const float* __restrict__ wT, const float* __restrict__ b,
    float* __restrict__ mask, int Hf, int Wf) {
  const int OH = 2 * Hf, OW = 2 * Wf;
  const int Np = OH * OW;
  int pix = blockIdx.x * TPB + threadIdx.x;
  if (pix >= Np) return;
  int x = pix % OW, y = pix / OW;
  const int fplane = Hf * Wf;

  float acc[25];
#pragma unroll
  for (int oc = 0; oc < 25; ++oc) acc[oc] = b[oc];   // uniform -> s_load

#pragma unroll
  for (int ky = 0; ky < 3; ++ky) {
    int yy = y + ky - 1;
    bool vy = (yy >= 0) && (yy < OH);
    int fy = yy >> 1;
#pragma unroll
    for (int kx = 0; kx < 3; ++kx) {
      int xx = x + kx - 1;
      bool vv = vy && (xx >= 0) && (xx < OW);
      int foff = fy * Wf + (xx >> 1);               // nearest2x source
      int hoff = yy * OW + xx;
      const float* wt = wT + (ky * 3 + kx) * 35 * 25;
      for (int ic = 0; ic < 32; ++ic) {             // runtime loop, small code
        float v = vv ? feat[ic * fplane + foff] : 0.0f;
        const float* wc = wt + ic * 25;             // uniform -> s_load_dwordx16/x8
#pragma unroll
        for (int oc = 0; oc < 25; ++oc) acc[oc] = fmaf(v, wc[oc], acc[oc]);
      }
#pragma unroll
      for (int ic = 0; ic < 3; ++ic) {
        float v = vv ? hf[ic * Np + hoff] : 0.0f;
        const float* wc = wt + (32 + ic) * 25;
#pragma unroll
        for (int oc = 0; oc < 25; ++oc) acc[oc] = fmaf(v, wc[oc], acc[oc]);
      }
    }
  }
  // softmax over the 25 taps + store
  float mx = acc[0];
#pragma unroll
  for (int oc = 1; oc < 25; ++oc) mx = fmaxf(mx, acc[oc]);
  float s = 0.f;
#pragma unroll
  for (int oc = 0; oc < 25; ++oc) { acc[oc] = __expf(acc[oc] - mx); s += acc[oc]; }
  float inv = 1.0f / s;
#pragma unroll
  for (int oc = 0; oc < 25; ++oc) mask[oc * Np + pix] = acc[oc] * inv;
}

// ---------- CARAFE on nearest2x input, folded to 3x3 source stencil
__device__ __forceinline__ void carafe_apply(
    const float* __restrict__ in, float* __restrict__ out, int C,
    int fplane, int Np, int pix, const float cw[9],
    const int sy[3], const int sx[3], int Wf) {
  for (int c = 0; c < C; ++c) {
    const float* p = in + c * fplane;
    const float* r0 = p + sy[0] * Wf;
    const float* r1 = p + sy[1] * Wf;
    const float* r2 = p + sy[2] * Wf;
    float acc = cw[0] * r0[sx[0]] + cw[1] * r0[sx[1]] + cw[2] * r0[sx[2]]
              + cw[3] * r1[sx[0]] + cw[4] * r1[sx[1]] + cw[5] * r1[sx[2]]
              + cw[6] * r2[sx[0]] + cw[7] * r2[sx[1]] + cw[8] * r2[sx[2]];
    out[c * Np + pix] = acc;
  }
}

__global__ __launch_bounds__(TPB) void carafe_kernel(
    const float* __restrict__ mask,
    const float* __restrict__ in0, float* __restrict__ out0, int C0,
    const float* __restrict__ in1, float* __restrict__ out1, int C1,
    int Hf, int Wf) {
  const int OH = 2 * Hf, OW = 2 * Wf;
  const int Np = OH * OW;
  int pix = blockIdx.x * TPB + threadIdx.x;
  if (pix >= Np) return;
  int x = pix % OW, y = pix / OW;

  float cw[9];
#pragma unroll
  for (int i = 0; i < 9; ++i) cw[i] = 0.f;
  int ry0 = (y - 2) >> 1, rx0 = (x - 2) >> 1;   // arithmetic shift = floor div
#pragma unroll
  for (int di = 0; di < 5; ++di) {
    int yy = y + di - 2;
    if (yy < 0 || yy >= OH) continue;           // zero-padding tap
    int ry = (yy >> 1) - ry0;                   // 0..2
#pragma unroll
    for (int dj = 0; dj < 5; ++dj) {
      int xx = x + dj - 2;
      if (xx < 0 || xx >= OW) continue;
      int rx = (xx >> 1) - rx0;
      cw[ry * 3 + rx] += mask[(di * 5 + dj) * Np + pix];
    }
  }
  int sy[3], sx[3];
#pragma unroll
  for (int i = 0; i < 3; ++i) {                 // clamp; OOB rows/cols have cw==0
    int v = ry0 + i; sy[i] = v < 0 ? 0 : (v >= Hf ? Hf - 1 : v);
    int u = rx0 + i; sx[i] = u < 0 ? 0 : (u >= Wf ? Wf - 1 : u);
  }
  const int fplane = Hf * Wf;
  carafe_apply(in0, out0, C0, fplane, Np, pix, cw, sy, sx, Wf);
  if (in1 != nullptr) carafe_apply(in1, out1, C1, fplane, Np, pix, cw, sy, sx, Wf);
}

extern "C" void kernel_launch(void* const* d_in, const int* in_sizes, int n_in,
                              void* d_out, int out_size, void* d_ws, size_t ws_size,
                              hipStream_t stream) {
  (void)in_sizes; (void)n_in; (void)out_size; (void)ws_size;
  const float* feat = (const float*)d_in[0];  // [1,32,96,96]
  const float* seg  = (const float*)d_in[1];  // [1,19,96,96]
  const float* img  = (const float*)d_in[2];  // [1,3,384,384]
  const float* w0   = (const float*)d_in[3];  // [25,35,3,3]
  const float* b0   = (const float*)d_in[4];  // [25]
  const float* w1   = (const float*)d_in[5];
  const float* b1   = (const float*)d_in[6];
  float* out = (float*)d_out;                 // [1,19,384,384]

  float* ws   = (float*)d_ws;
  float* I192 = ws;                    // 3*192*192
  float* I96  = I192 + 3 * 192 * 192;  // 3*96*96
  float* HF   = I96  + 3 * 96 * 96;    // up to 3*384*384
  float* MASK = HF   + 3 * 384 * 384;  // up to 25*384*384
  float* F1   = MASK + 25 * 384 * 384; // 32*192*192
  float* S1   = F1   + 32 * 192 * 192; // 19*192*192
  float* WT0  = S1   + 19 * 192 * 192; // 7875
  float* WT1  = WT0  + 7875;           // 7875
  // total ~24.7 MB of workspace

  // weight repack (tiny) + shared pre-pass
  repack_w_kernel<<<31, TPB, 0, stream>>>(w0, WT0);
  repack_w_kernel<<<31, TPB, 0, stream>>>(w1, WT1);
  down2_kernel<<<432, TPB, 0, stream>>>(img, I192, 3, 192, 192);
  down2_kernel<<<108, TPB, 0, stream>>>(I192, I96, 3, 96, 96);

  // ---- iteration 0 (Hf=96) ----
  highboost_kernel<<<432, TPB, 0, stream>>>(I192, I96, HF, 3, 96, 96);
  conv_softmax_kernel<<<(96 * 96 * 4 + TPB - 1) / TPB, TPB, 0, stream>>>(
      feat, HF, WT0, b0, MASK, 96, 96);
  carafe_kernel<<<(96 * 96 * 4 + TPB - 1) / TPB, TPB, 0, stream>>>(
      MASK, seg, S1, 19, feat, F1, 32, 96, 96);

  // ---- iteration 1 (Hf=192) ----
  highboost_kernel<<<1728, TPB, 0, stream>>>(img, I192, HF, 3, 192, 192);
  conv_softmax_kernel<<<(192 * 192 * 4 + TPB - 1) / TPB, TPB, 0, stream>>>(
      F1, HF, WT1, b1, MASK, 192, 192);
  carafe_kernel<<<(192 * 192 * 4 + TPB - 1) / TPB, TPB, 0, stream>>>(
      MASK, S1, out, 19, nullptr, nullptr, 0, 192, 192);
}

// Round 9
// 178.085 us; speedup vs baseline: 7.6566x; 1.8804x over previous
//
#include <hip/hip_runtime.h>

// CascadeImageGuideUpsample. R4 conv redesign:
//  - parity-fold: per output-pixel parity the 3x3 conv over nearest2x(feat)
//    reads only a 2x2 source patch -> fold 9 tap weights into 4 per
//    (parity, ic, oc). Zero-padding exact: per parity the invalid border tap
//    is the sole contributor to its 2x2 slot -> zero that source value.
//  - K-split: block = 8 waves x 64 same-parity pixels; each wave accumulates
//    a channel slice (weights wave-uniform -> s_load), LDS reduce + softmax.

#define TPB 256

// ---- repack: W2[((p*32+ic)*4+src)*25+oc] (parity-folded feat weights),
//      wTh[(tap*3+h)*25+oc] (hf per-tap weights). w is [25,35,3,3].
__global__ __launch_bounds__(TPB) void repack_kernel(
    const float* __restrict__ w, float* __restrict__ W2, float* __restrict__ wTh) {
  int i = blockIdx.x * TPB + threadIdx.x;
  if (i < 12800) {
    int oc = i % 25; int j = i / 25;
    int src = j & 3; j >>= 2;
    int ic = j & 31; int p = j >> 5;       // parity 0..3 = (py*2+px)
    int py = p >> 1, px = p & 1;
    int a = src >> 1, b = src & 1;
    float s = 0.f;
    for (int ky = 0; ky < 3; ++ky) {
      int rs = (py == 0) ? (ky >= 1) : (ky >= 2);
      if (rs != a) continue;
      for (int kx = 0; kx < 3; ++kx) {
        int cs = (px == 0) ? (kx >= 1) : (kx >= 2);
        if (cs != b) continue;
        s += w[oc * 315 + ic * 9 + ky * 3 + kx];
      }
    }
    W2[i] = s;
  } else if (i < 12800 + 675) {
    int k = i - 12800;
    int oc = k % 25; int j = k / 25;
    int h = j % 3; int tap = j / 3;
    wTh[k] = w[oc * 315 + (32 + h) * 9 + tap];
  }
}

// ---- down2: out[c,y,x] = avg of 2x2 block. out [C,H,W], in [C,2H,2W]
__global__ __launch_bounds__(TPB) void down2_kernel(
    const float* __restrict__ in, float* __restrict__ out, int C, int H, int W) {
  int idx = blockIdx.x * blockDim.x + threadIdx.x;
  int N = C * H * W;
  if (idx >= N) return;
  int x = idx % W; int t = idx / W; int y = t % H; int c = t / H;
  const float* p = in + ((c * 2 * H) + 2 * y) * (2 * W) + 2 * x;
  out[idx] = 0.25f * (p[0] + p[1] + p[2 * W] + p[2 * W + 1]);
}

// ---- highboost: out = 2*base - up2(lr). base/out [C,2H,2W], lr [C,H,W]
__global__ __launch_bounds__(TPB) void highboost_kernel(
    const float* __restrict__ base, const float* __restrict__ lr,
    float* __restrict__ out, int C, int H, int W) {
  const int OH = 2 * H, OW = 2 * W;
  int idx = blockIdx.x * blockDim.x + threadIdx.x;
  int N = C * OH * OW;
  if (idx >= N) return;
  int x = idx % OW; int t = idx / OW; int y = t % OH; int c = t / OH;
  int m = y >> 1; int ya, yb; float wya, wyb;
  if ((y & 1) == 0) { ya = (m - 1 < 0) ? 0 : m - 1; yb = m; wya = 0.25f; wyb = 0.75f; }
  else             { ya = m; yb = (m + 1 >= H) ? H - 1 : m + 1; wya = 0.75f; wyb = 0.25f; }
  int n = x >> 1; int xa, xb; float wxa, wxb;
  if ((x & 1) == 0) { xa = (n - 1 < 0) ? 0 : n - 1; xb = n; wxa = 0.25f; wxb = 0.75f; }
  else             { xa = n; xb = (n + 1 >= W) ? W - 1 : n + 1; wxa = 0.75f; wxb = 0.25f; }
  const float* p = lr + c * H * W;
  float up = wya * (wxa * p[ya * W + xa] + wxb * p[ya * W + xb])
           + wyb * (wxa * p[yb * W + xa] + wxb * p[yb * W + xb]);
  out[idx] = 2.0f * base[idx] - up;
}

// ---- conv3x3(concat(nearest2x(feat), hf)) + softmax over 25 channels.
// Grid: 4 parities x (Hf/2) x (Wf/32) blocks; block = 512 thr = 8 waves.
// Wave = K-slice over 64 same-parity pixels (2 gy-rows x 32 gx-cols).
// Slices: s0..s2: 3 feat ch + 1 hf ch; s3..s7: 5 feat ch.
__global__ __launch_bounds__(512, 4) void conv_softmax_kernel(
    const float* __restrict__ feat, const float* __restrict__ hf,
    const float* __restrict__ W2, const float* __restrict__ wTh,
    const float* __restrict__ b, float* __restrict__ mask,
    int Hf, int Wf) {
  const int OH = 2 * Hf, OW = 2 * Wf, Np = OH * OW, fplane = Hf * Wf;
  __shared__ float red[8][64][26];

  const int t = threadIdx.x;
  const int lane = t & 63;
  const int s = __builtin_amdgcn_readfirstlane(t >> 6);  // wave id, uniform
  const int par = blockIdx.x & 3;
  const int bt = blockIdx.x >> 2;
  const int TW = Wf >> 5;
  const int gx0 = (bt % TW) << 5;
  const int gy0 = (bt / TW) << 1;
  const int py = par >> 1, px = par & 1;
  const int gy = gy0 + (lane >> 5);
  const int gx = gx0 + (lane & 31);

  // 2x2 source rows/cols + border-zero flags (exact zero-padding)
  int r0 = gy - 1 + py; const bool zr0 = (r0 < 0);      if (zr0) r0 = 0;
  int r1 = gy + py;     const bool zr1 = (r1 >= Hf);    if (zr1) r1 = Hf - 1;
  int c0 = gx - 1 + px; const bool zc0 = (c0 < 0);      if (zc0) c0 = 0;
  int c1 = gx + px;     const bool zc1 = (c1 >= Wf);    if (zc1) c1 = Wf - 1;
  const int o00 = r0 * Wf + c0, o01 = r0 * Wf + c1;
  const int o10 = r1 * Wf + c0, o11 = r1 * Wf + c1;

  float acc[25];
#pragma unroll
  for (int oc = 0; oc < 25; ++oc) acc[oc] = 0.f;

  const int fbeg_tab[8] = {0, 3, 6, 9, 14, 19, 24, 28};
  const int fend_tab[8] = {3, 6, 9, 14, 19, 24, 28, 32};
  const int fbeg = fbeg_tab[s], fend = fend_tab[s];

  for (int ic = fbeg; ic < fend; ++ic) {
    const float* fp = feat + ic * fplane;
    float v00 = (zr0 | zc0) ? 0.f : fp[o00];
    float v01 = (zr0 | zc1) ? 0.f : fp[o01];
    float v10 = (zr1 | zc0) ? 0.f : fp[o10];
    float v11 = (zr1 | zc1) ? 0.f : fp[o11];
    const float* wp = W2 + (size_t)((par * 32 + ic) * 4) * 25;  // uniform -> s_load
#pragma unroll
    for (int oc = 0; oc < 25; ++oc)
      acc[oc] += v00 * wp[oc] + v01 * wp[25 + oc] + v10 * wp[50 + oc] + v11 * wp[75 + oc];
  }

  if (s < 3) {  // hf channel s, per-tap (no fold possible at up-res)
    const int x = 2 * gx + px, y = 2 * gy + py;
    const float* hp = hf + s * Np;
#pragma unroll
    for (int ky = 0; ky < 3; ++ky) {
      int yy = y + ky - 1;
      bool vy = (yy >= 0) && (yy < OH);
      int yo = (vy ? yy : 0) * OW;
#pragma unroll
      for (int kx = 0; kx < 3; ++kx) {
        int xx = x + kx - 1;
        bool vv = vy && (xx >= 0) && (xx < OW);
        float v = vv ? hp[yo + (vv ? xx : 0)] : 0.f;
        const float* wp = wTh + ((ky * 3 + kx) * 3 + s) * 25;   // uniform -> s_load
#pragma unroll
        for (int oc = 0; oc < 25; ++oc) acc[oc] = fmaf(v, wp[oc], acc[oc]);
      }
    }
  }

  // LDS reduce over 8 slices + bias
#pragma unroll
  for (int oc = 0; oc < 25; ++oc) red[s][lane][oc] = acc[oc];
  __syncthreads();
  for (int i = t; i < 1600; i += 512) {
    int oc = i % 25, p2 = i / 25;
    float sum = red[0][p2][oc];
#pragma unroll
    for (int k = 1; k < 8; ++k) sum += red[k][p2][oc];
    red[0][p2][oc] = sum + b[oc];
  }
  __syncthreads();
  // softmax per pixel (wave 0)
  if (t < 64) {
    float mx = red[0][t][0];
#pragma unroll
    for (int oc = 1; oc < 25; ++oc) mx = fmaxf(mx, red[0][t][oc]);
    float ssum = 0.f;
#pragma unroll
    for (int oc = 0; oc < 25; ++oc) {
      float e = __expf(red[0][t][oc] - mx); red[0][t][oc] = e; ssum += e;
    }
    float inv = 1.0f / ssum;
#pragma unroll
    for (int oc = 0; oc < 25; ++oc) red[0][t][oc] *= inv;
  }
  __syncthreads();
  // store (plane-major mask, stride-2 x within a lane-run)
  {
    const int p2 = t & 63;
    const int gy2 = gy0 + (p2 >> 5), gx2 = gx0 + (p2 & 31);
    const int pix = (2 * gy2 + py) * OW + (2 * gx2 + px);
    for (int oc = s; oc < 25; oc += 8)
      mask[oc * Np + pix] = red[0][p2][oc];
  }
}

// ---- CARAFE on nearest2x input, folded to 3x3 source stencil
__device__ __forceinline__ void carafe_apply(
    const float* __restrict__ in, float* __restrict__ out, int C,
    int fplane, int Np, int pix, const float cw[9],
    const int sy[3], const int sx[3], int Wf) {
  for (int c = 0; c < C; ++c) {
    const float* p = in + c * fplane;
    const float* r0 = p + sy[0] * Wf;
    const float* r1 = p + sy[1] * Wf;
    const float* r2 = p + sy[2] * Wf;
    float acc = cw[0] * r0[sx[0]] + cw[1] * r0[sx[1]] + cw[2] * r0[sx[2]]
              + cw[3] * r1[sx[0]] + cw[4] * r1[sx[1]] + cw[5] * r1[sx[2]]
              + cw[6] * r2[sx[0]] + cw[7] * r2[sx[1]] + cw[8] * r2[sx[2]];
    out[c * Np + pix] = acc;
  }
}

__global__ __launch_bounds__(TPB) void carafe_kernel(
    const float* __restrict__ mask,
    const float* __restrict__ in0, float* __restrict__ out0, int C0,
    const float* __restrict__ in1, float* __restrict__ out1, int C1,
    int Hf, int Wf) {
  const int OH = 2 * Hf, OW = 2 * Wf;
  const int Np = OH * OW;
  int pix = blockIdx.x * blockDim.x + threadIdx.x;
  if (pix >= Np) return;
  int x = pix % OW, y = pix / OW;

  float cw[9];
#pragma unroll
  for (int i = 0; i < 9; ++i) cw[i] = 0.f;
  int ry0 = (y - 2) >> 1, rx0 = (x - 2) >> 1;
#pragma unroll
  for (int di = 0; di < 5; ++di) {
    int yy = y + di - 2;
    if (yy < 0 || yy >= OH) continue;
#pragma unroll
    for (int dj = 0; dj < 5; ++dj) {
      int xx = x + dj - 2;
      if (xx < 0 || xx >= OW) continue;
      int rx = (xx >> 1) - rx0;
      cw[((yy >> 1) - ry0) * 3 + rx] += mask[(di * 5 + dj) * Np + pix];
    }
  }
  int sy[3], sx[3];
#pragma unroll
  for (int i = 0; i < 3; ++i) {
    int v = ry0 + i; sy[i] = v < 0 ? 0 : (v >= Hf ? Hf - 1 : v);
    int u = rx0 + i; sx[i] = u < 0 ? 0 : (u >= Wf ? Wf - 1 : u);
  }
  const int fplane = Hf * Wf;
  carafe_apply(in0, out0, C0, fplane, Np, pix, cw, sy, sx, Wf);
  if (in1 != nullptr) carafe_apply(in1, out1, C1, fplane, Np, pix, cw, sy, sx, Wf);
}

extern "C" void kernel_launch(void* const* d_in, const int* in_sizes, int n_in,
                              void* d_out, int out_size, void* d_ws, size_t ws_size,
                              hipStream_t stream) {
  (void)in_sizes; (void)n_in; (void)out_size; (void)ws_size;
  const float* feat = (const float*)d_in[0];  // [1,32,96,96]
  const float* seg  = (const float*)d_in[1];  // [1,19,96,96]
  const float* img  = (const float*)d_in[2];  // [1,3,384,384]
  const float* w0   = (const float*)d_in[3];  // [25,35,3,3]
  const float* b0   = (const float*)d_in[4];  // [25]
  const float* w1   = (const float*)d_in[5];
  const float* b1   = (const float*)d_in[6];
  float* out = (float*)d_out;                 // [1,19,384,384]

  float* ws   = (float*)d_ws;
  float* I192 = ws;                    // 3*192*192
  float* I96  = I192 + 3 * 192 * 192;  // 3*96*96
  float* HF   = I96  + 3 * 96 * 96;    // 3*384*384 max
  float* MASK = HF   + 3 * 384 * 384;  // 25*384*384 max
  float* F1   = MASK + 25 * 384 * 384; // 32*192*192
  float* S1   = F1   + 32 * 192 * 192; // 19*192*192
  float* W2_0 = S1   + 19 * 192 * 192; // 12800
  float* WTH0 = W2_0 + 12800;          // 675
  float* W2_1 = WTH0 + 675;            // 12800
  float* WTH1 = W2_1 + 12800;          // 675

  repack_kernel<<<53, TPB, 0, stream>>>(w0, W2_0, WTH0);
  repack_kernel<<<53, TPB, 0, stream>>>(w1, W2_1, WTH1);
  down2_kernel<<<1728, 64, 0, stream>>>(img, I192, 3, 192, 192);
  down2_kernel<<<432, 64, 0, stream>>>(I192, I96, 3, 96, 96);

  // ---- iteration 0 (Hf=96) ----
  highboost_kernel<<<1728, 64, 0, stream>>>(I192, I96, HF, 3, 96, 96);
  conv_softmax_kernel<<<4 * 48 * 3, 512, 0, stream>>>(
      feat, HF, W2_0, WTH0, b0, MASK, 96, 96);
  carafe_kernel<<<576, 64, 0, stream>>>(
      MASK, seg, S1, 19, feat, F1, 32, 96, 96);

  // ---- iteration 1 (Hf=192) ----
  highboost_kernel<<<6912, 64, 0, stream>>>(img, I192, HF, 3, 192, 192);
  conv_softmax_kernel<<<4 * 96 * 6, 512, 0, stream>>>(
      F1, HF, W2_1, WTH1, b1, MASK, 192, 192);
  carafe_kernel<<<2304, 64, 0, stream>>>(
      MASK, S1, out, 19, nullptr, nullptr, 0, 192, 192);
}

// Round 10
// 175.642 us; speedup vs baseline: 7.7631x; 1.0139x over previous
//
#include <hip/hip_runtime.h>

// CascadeImageGuideUpsample, R9:
//  - conv_softmax now emits the FOLDED 9-tap CARAFE weights (CW) directly
//    (25->9 fold is per-pixel; tap->slot map is static given parity since
//    ry0 = gy-1 exactly). Saves 40% mask traffic + all fold work in carafe.
//  - carafe: channel-chunked via gridDim.y (more blocks, shorter chains).
//  - launches 10->8: merged repack (both weight sets), down2#2 fused into hf0.

// ---- repack both weight sets: W2[((p*32+ic)*4+src)*25+oc], wTh[(tap*3+h)*25+oc]
__global__ __launch_bounds__(256) void repack_kernel(
    const float* __restrict__ w0s, const float* __restrict__ w1s,
    float* __restrict__ W2a, float* __restrict__ wTha,
    float* __restrict__ W2b, float* __restrict__ wThb) {
  int i = blockIdx.x * 256 + threadIdx.x;
  const float* w; float* W2; float* wTh; int k = i;
  if (i < 13475) { w = w0s; W2 = W2a; wTh = wTha; }
  else { k = i - 13475; if (k >= 13475) return; w = w1s; W2 = W2b; wTh = wThb; }
  if (k < 12800) {
    int oc = k % 25; int j = k / 25;
    int src = j & 3; j >>= 2;
    int ic = j & 31; int p = j >> 5;       // parity 0..3 = (py*2+px)
    int py = p >> 1, px = p & 1;
    int a = src >> 1, b = src & 1;
    float s = 0.f;
    for (int ky = 0; ky < 3; ++ky) {
      int rs = (py == 0) ? (ky >= 1) : (ky >= 2);
      if (rs != a) continue;
      for (int kx = 0; kx < 3; ++kx) {
        int cs = (px == 0) ? (kx >= 1) : (kx >= 2);
        if (cs != b) continue;
        s += w[oc * 315 + ic * 9 + ky * 3 + kx];
      }
    }
    W2[k] = s;
  } else {
    int kk = k - 12800;
    int oc = kk % 25; int j = kk / 25;
    int h = j % 3; int tap = j / 3;
    wTh[kk] = w[oc * 315 + (32 + h) * 9 + tap];
  }
}

// ---- down2: out[c,y,x] = avg of 2x2. out [3,192,192], in [3,384,384]
__global__ __launch_bounds__(256) void down2_kernel(
    const float* __restrict__ in, float* __restrict__ out) {
  int idx = blockIdx.x * 256 + threadIdx.x;
  if (idx >= 3 * 192 * 192) return;
  int x = idx % 192; int t = idx / 192; int y = t % 192; int c = t / 192;
  const float* p = in + (c * 384 + 2 * y) * 384 + 2 * x;
  out[idx] = 0.25f * (p[0] + p[1] + p[384] + p[385]);
}

// ---- hf0: out = 2*I192 - up2(down2(I192)), I96 taps computed on the fly.
__global__ __launch_bounds__(256) void hf0_kernel(
    const float* __restrict__ I192, float* __restrict__ out) {
  int idx = blockIdx.x * 256 + threadIdx.x;
  if (idx >= 3 * 192 * 192) return;
  int x = idx % 192; int t = idx / 192; int y = t % 192; int c = t / 192;
  int m = y >> 1; int ya, yb; float wya, wyb;
  if ((y & 1) == 0) { ya = m - 1 < 0 ? 0 : m - 1; yb = m; wya = 0.25f; wyb = 0.75f; }
  else             { ya = m; yb = m + 1 > 95 ? 95 : m + 1; wya = 0.75f; wyb = 0.25f; }
  int n = x >> 1; int xa, xb; float wxa, wxb;
  if ((x & 1) == 0) { xa = n - 1 < 0 ? 0 : n - 1; xb = n; wxa = 0.25f; wxb = 0.75f; }
  else             { xa = n; xb = n + 1 > 95 ? 95 : n + 1; wxa = 0.75f; wxb = 0.25f; }
  const float* base = I192 + c * 192 * 192;
  auto I96v = [&](int mm, int nn) {
    const float* p = base + (2 * mm) * 192 + 2 * nn;
    return 0.25f * (p[0] + p[1] + p[192] + p[193]);
  };
  float up = wya * (wxa * I96v(ya, xa) + wxb * I96v(ya, xb))
           + wyb * (wxa * I96v(yb, xa) + wxb * I96v(yb, xb));
  out[idx] = 2.0f * base[y * 192 + x] - up;
}

// ---- highboost (iter-1): out = 2*img - up2(I192). base [3,384,384], lr [3,192,192]
__global__ __launch_bounds__(256) void highboost_kernel(
    const float* __restrict__ base, const float* __restrict__ lr,
    float* __restrict__ out) {
  const int H = 192, OW = 384;
  int idx = blockIdx.x * 256 + threadIdx.x;
  if (idx >= 3 * 384 * 384) return;
  int x = idx % OW; int t = idx / OW; int y = t % 384; int c = t / 384;
  int m = y >> 1; int ya, yb; float wya, wyb;
  if ((y & 1) == 0) { ya = m - 1 < 0 ? 0 : m - 1; yb = m; wya = 0.25f; wyb = 0.75f; }
  else             { ya = m; yb = m + 1 >= H ? H - 1 : m + 1; wya = 0.75f; wyb = 0.25f; }
  int n = x >> 1; int xa, xb; float wxa, wxb;
  if ((x & 1) == 0) { xa = n - 1 < 0 ? 0 : n - 1; xb = n; wxa = 0.25f; wxb = 0.75f; }
  else             { xa = n; xb = n + 1 >= H ? H - 1 : n + 1; wxa = 0.75f; wxb = 0.25f; }
  const float* p = lr + c * H * H;
  float up = wya * (wxa * p[ya * H + xa] + wxb * p[ya * H + xb])
           + wyb * (wxa * p[yb * H + xa] + wxb * p[yb * H + xb]);
  out[idx] = 2.0f * base[idx] - up;
}

// ---- conv3x3(concat(nearest2x(feat), hf)) + softmax + 25->9 fold -> CW planes.
// Grid: 4 parities x (Hf/2) x (Wf/32); block = 512 thr = 8 waves.
// Slices: s0..s2: 2 feat + 1 hf; s3: 6 feat; s4..s7: 5 feat.
__global__ __launch_bounds__(512, 4) void conv_softmax_kernel(
    const float* __restrict__ feat, const float* __restrict__ hf,
    const float* __restrict__ W2, const float* __restrict__ wTh,
    const float* __restrict__ b, float* __restrict__ CW,
    int Hf, int Wf) {
  const int OH = 2 * Hf, OW = 2 * Wf, Np = OH * OW, fplane = Hf * Wf;
  __shared__ float red[8][64][26];

  const int t = threadIdx.x;
  const int lane = t & 63;
  const int s = __builtin_amdgcn_readfirstlane(t >> 6);  // wave id, uniform
  const int par = blockIdx.x & 3;
  const int bt = blockIdx.x >> 2;
  const int TW = Wf >> 5;
  const int gx0 = (bt % TW) << 5;
  const int gy0 = (bt / TW) << 1;
  const int py = par >> 1, px = par & 1;
  const int gy = gy0 + (lane >> 5);
  const int gx = gx0 + (lane & 31);

  // 2x2 source rows/cols + border-zero flags (exact zero-padding)
  int r0 = gy - 1 + py; const bool zr0 = (r0 < 0);      if (zr0) r0 = 0;
  int r1 = gy + py;     const bool zr1 = (r1 >= Hf);    if (zr1) r1 = Hf - 1;
  int c0 = gx - 1 + px; const bool zc0 = (c0 < 0);      if (zc0) c0 = 0;
  int c1 = gx + px;     const bool zc1 = (c1 >= Wf);    if (zc1) c1 = Wf - 1;
  const int o00 = r0 * Wf + c0, o01 = r0 * Wf + c1;
  const int o10 = r1 * Wf + c0, o11 = r1 * Wf + c1;

  float acc[25];
#pragma unroll
  for (int oc = 0; oc < 25; ++oc) acc[oc] = 0.f;

  // uniform slice bounds (scalar cndmask chain, no memory)
  const int fbeg = s == 0 ? 0 : s == 1 ? 2 : s == 2 ? 4 : s == 3 ? 6
                 : s == 4 ? 12 : s == 5 ? 17 : s == 6 ? 22 : 27;
  const int fend = s == 0 ? 2 : s == 1 ? 4 : s == 2 ? 6 : s == 3 ? 12
                 : s == 4 ? 17 : s == 5 ? 22 : s == 6 ? 27 : 32;

  for (int ic = fbeg; ic < fend; ++ic) {
    const float* fp = feat + ic * fplane;
    float v00 = (zr0 | zc0) ? 0.f : fp[o00];
    float v01 = (zr0 | zc1) ? 0.f : fp[o01];
    float v10 = (zr1 | zc0) ? 0.f : fp[o10];
    float v11 = (zr1 | zc1) ? 0.f : fp[o11];
    const float* wp = W2 + (size_t)((par * 32 + ic) * 4) * 25;  // uniform -> s_load
#pragma unroll
    for (int oc = 0; oc < 25; ++oc)
      acc[oc] += v00 * wp[oc] + v01 * wp[25 + oc] + v10 * wp[50 + oc] + v11 * wp[75 + oc];
  }

  if (s < 3) {  // hf channel s, per-tap
    const int x = 2 * gx + px, y = 2 * gy + py;
    const float* hp = hf + s * Np;
#pragma unroll
    for (int ky = 0; ky < 3; ++ky) {
      int yy = y + ky - 1;
      bool vy = (yy >= 0) && (yy < OH);
      int yo = (vy ? yy : 0) * OW;
#pragma unroll
      for (int kx = 0; kx < 3; ++kx) {
        int xx = x + kx - 1;
        bool vv = vy && (xx >= 0) && (xx < OW);
        float v = vv ? hp[yo + (vv ? xx : 0)] : 0.f;
        const float* wp = wTh + ((ky * 3 + kx) * 3 + s) * 25;   // uniform -> s_load
#pragma unroll
        for (int oc = 0; oc < 25; ++oc) acc[oc] = fmaf(v, wp[oc], acc[oc]);
      }
    }
  }

  // LDS reduce over 8 slices + bias
#pragma unroll
  for (int oc = 0; oc < 25; ++oc) red[s][lane][oc] = acc[oc];
  __syncthreads();
  for (int i = t; i < 1600; i += 512) {
    int oc = i % 25, p2 = i / 25;
    float sum = red[0][p2][oc];
#pragma unroll
    for (int k = 1; k < 8; ++k) sum += red[k][p2][oc];
    red[0][p2][oc] = sum + b[oc];
  }
  __syncthreads();

  // wave 0: softmax in regs, fold 25->9 (static map given parity), store CW
  if (t < 64) {
    const int gy2 = gy0 + (t >> 5), gx2 = gx0 + (t & 31);
    const int y = 2 * gy2 + py, x = 2 * gx2 + px;
    float m[25];
#pragma unroll
    for (int oc = 0; oc < 25; ++oc) m[oc] = red[0][t][oc];
    float mx = m[0];
#pragma unroll
    for (int oc = 1; oc < 25; ++oc) mx = fmaxf(mx, m[oc]);
    float ssum = 0.f;
#pragma unroll
    for (int oc = 0; oc < 25; ++oc) { m[oc] = __expf(m[oc] - mx); ssum += m[oc]; }
    float inv = 1.0f / ssum;

    // validity masks (zero-padding taps)
    bool vy[5], vx[5];
#pragma unroll
    for (int d = 0; d < 5; ++d) {
      vy[d] = (unsigned)(y + d - 2) < (unsigned)OH;
      vx[d] = (unsigned)(x + d - 2) < (unsigned)OW;
    }
    float rs[3][5];   // vertical fold; indices all compile-time per branch
    if (py == 0) {
#pragma unroll
      for (int dj = 0; dj < 5; ++dj) {
        float m0 = (vy[0] && vx[dj]) ? m[0 + dj] : 0.f;
        float m1 = (vy[1] && vx[dj]) ? m[5 + dj] : 0.f;
        float m2 = (vy[2] && vx[dj]) ? m[10 + dj] : 0.f;
        float m3 = (vy[3] && vx[dj]) ? m[15 + dj] : 0.f;
        float m4 = (vy[4] && vx[dj]) ? m[20 + dj] : 0.f;
        rs[0][dj] = m0 + m1; rs[1][dj] = m2 + m3; rs[2][dj] = m4;
      }
    } else {
#pragma unroll
      for (int dj = 0; dj < 5; ++dj) {
        float m0 = (vy[0] && vx[dj]) ? m[0 + dj] : 0.f;
        float m1 = (vy[1] && vx[dj]) ? m[5 + dj] : 0.f;
        float m2 = (vy[2] && vx[dj]) ? m[10 + dj] : 0.f;
        float m3 = (vy[3] && vx[dj]) ? m[15 + dj] : 0.f;
        float m4 = (vy[4] && vx[dj]) ? m[20 + dj] : 0.f;
        rs[0][dj] = m0; rs[1][dj] = m1 + m2; rs[2][dj] = m3 + m4;
      }
    }
    float cw[9];
#pragma unroll
    for (int r = 0; r < 3; ++r) {
      if (px == 0) {
        cw[r * 3 + 0] = rs[r][0] + rs[r][1];
        cw[r * 3 + 1] = rs[r][2] + rs[r][3];
        cw[r * 3 + 2] = rs[r][4];
      } else {
        cw[r * 3 + 0] = rs[r][0];
        cw[r * 3 + 1] = rs[r][1] + rs[r][2];
        cw[r * 3 + 2] = rs[r][3] + rs[r][4];
      }
    }
    const int pix = y * OW + x;
#pragma unroll
    for (int tap = 0; tap < 9; ++tap) CW[tap * Np + pix] = cw[tap] * inv;
  }
}

// ---- CARAFE applying precomputed folded weights. Channel-chunked by gridDim.y:
// global channel range [blockIdx.y*CS, ...) over concat(in0:C0, in1:C1).
__global__ __launch_bounds__(256) void carafe_kernel(
    const float* __restrict__ CW,
    const float* __restrict__ in0, float* __restrict__ out0, int C0,
    const float* __restrict__ in1, float* __restrict__ out1, int C1,
    int CS, int Hf, int Wf) {
  const int OW = 2 * Wf;
  const int Np = 4 * Hf * Wf;
  int pix = blockIdx.x * 256 + threadIdx.x;
  if (pix >= Np) return;
  int x = pix % OW, y = pix / OW;
  int ry0 = (y >> 1) - 1, rx0 = (x >> 1) - 1;
  int sy[3], sx[3];
#pragma unroll
  for (int i = 0; i < 3; ++i) {     // clamp; OOB rows/cols have cw==0
    int v = ry0 + i; sy[i] = v < 0 ? 0 : (v >= Hf ? Hf - 1 : v);
    int u = rx0 + i; sx[i] = u < 0 ? 0 : (u >= Wf ? Wf - 1 : u);
  }
  float cw[9];
#pragma unroll
  for (int i = 0; i < 9; ++i) cw[i] = CW[i * Np + pix];
  const int fplane = Hf * Wf;
  int cbeg = blockIdx.y * CS;
  int cend = cbeg + CS; int Ct = C0 + C1; if (cend > Ct) cend = Ct;
  for (int c = cbeg; c < cend; ++c) {
    const float* p; float* q;
    if (c < C0) { p = in0 + c * fplane; q = out0 + c * Np; }
    else        { p = in1 + (c - C0) * fplane; q = out1 + (c - C0) * Np; }
    const float* r0 = p + sy[0] * Wf;
    const float* r1 = p + sy[1] * Wf;
    const float* r2 = p + sy[2] * Wf;
    float acc = cw[0] * r0[sx[0]] + cw[1] * r0[sx[1]] + cw[2] * r0[sx[2]]
              + cw[3] * r1[sx[0]] + cw[4] * r1[sx[1]] + cw[5] * r1[sx[2]]
              + cw[6] * r2[sx[0]] + cw[7] * r2[sx[1]] + cw[8] * r2[sx[2]];
    q[pix] = acc;
  }
}

extern "C" void kernel_launch(void* const* d_in, const int* in_sizes, int n_in,
                              void* d_out, int out_size, void* d_ws, size_t ws_size,
                              hipStream_t stream) {
  (void)in_sizes; (void)n_in; (void)out_size; (void)ws_size;
  const float* feat = (const float*)d_in[0];  // [1,32,96,96]
  const float* seg  = (const float*)d_in[1];  // [1,19,96,96]
  const float* img  = (const float*)d_in[2];  // [1,3,384,384]
  const float* w0   = (const float*)d_in[3];  // [25,35,3,3]
  const float* b0   = (const float*)d_in[4];  // [25]
  const float* w1   = (const float*)d_in[5];
  const float* b1   = (const float*)d_in[6];
  float* out = (float*)d_out;                 // [1,19,384,384]

  float* ws   = (float*)d_ws;
  float* I192 = ws;                    // 3*192*192   = 110592
  float* HF   = I192 + 3 * 192 * 192;  // 3*384*384 max = 442368
  float* CWb  = HF   + 3 * 384 * 384;  // 9*384*384 max = 1327104
  float* F1   = CWb  + 9 * 384 * 384;  // 32*192*192  = 1179648
  float* S1   = F1   + 32 * 192 * 192; // 19*192*192  = 700416
  float* W2_0 = S1   + 19 * 192 * 192; // 12800
  float* WTH0 = W2_0 + 12800;          // 675
  float* W2_1 = WTH0 + 675;            // 12800
  float* WTH1 = W2_1 + 12800;          // 675
  // total ~15.1 MB of workspace

  repack_kernel<<<106, 256, 0, stream>>>(w0, w1, W2_0, WTH0, W2_1, WTH1);
  down2_kernel<<<432, 256, 0, stream>>>(img, I192);

  // ---- iteration 0 (Hf=96) ----
  hf0_kernel<<<432, 256, 0, stream>>>(I192, HF);
  conv_softmax_kernel<<<4 * 48 * 3, 512, 0, stream>>>(
      feat, HF, W2_0, WTH0, b0, CWb, 96, 96);
  carafe_kernel<<<dim3(144, 3), 256, 0, stream>>>(
      CWb, seg, S1, 19, feat, F1, 32, 17, 96, 96);

  // ---- iteration 1 (Hf=192) ----
  highboost_kernel<<<1728, 256, 0, stream>>>(img, I192, HF);
  conv_softmax_kernel<<<4 * 96 * 6, 512, 0, stream>>>(
      F1, HF, W2_1, WTH1, b1, CWb, 192, 192);
  carafe_kernel<<<dim3(576, 2), 256, 0, stream>>>(
      CWb, S1, out, 19, nullptr, nullptr, 0, 10, 192, 192);
}